// Round 8
// baseline (523.282 us; speedup 1.0000x reference)
//
#include <hip/hip_runtime.h>
#include <hip/hip_fp16.h>

#define G 64
#define KNN 8
#define PAD 66

typedef _Float16 f16x2 __attribute__((ext_vector_type(2)));
typedef _Float16 f16x8 __attribute__((ext_vector_type(8)));
typedef float f32x16 __attribute__((ext_vector_type(16)));

static __device__ __forceinline__ f16x2 pkrtz(float a, float b) {
    return __builtin_bit_cast(f16x2, __builtin_amdgcn_cvt_pkrtz(a, b));
}
static __device__ __forceinline__ void plswap(f16x2& a, f16x2& b) {
    int ai = __builtin_bit_cast(int, a), bi = __builtin_bit_cast(int, b);
    asm("v_permlane32_swap_b32 %0, %1" : "+v"(ai), "+v"(bi));
    a = __builtin_bit_cast(f16x2, ai);
    b = __builtin_bit_cast(f16x2, bi);
}
static __device__ __forceinline__ void gload_lds16(const void* g, void* l) {
    __builtin_amdgcn_global_load_lds(
        (const __attribute__((address_space(1))) void*)g,
        (__attribute__((address_space(3))) void*)l, 16, 0, 0);
}

// ---------------------------------------------------------------------------
// Kernel 1: per-point MLP + scatter (unchanged, passing since round 6).
// ---------------------------------------------------------------------------
__global__ __launch_bounds__(256) void point_mlp_scatter(
    const float* __restrict__ pos, const int* __restrict__ pts,
    const float* __restrict__ W1, const float* __restrict__ b1,
    const float* __restrict__ W2, const float* __restrict__ b2,
    const float* __restrict__ Wk1, const float* __restrict__ bk1,
    const float* __restrict__ Wk2, const float* __restrict__ bk2,
    float* __restrict__ sums, float* __restrict__ cnt, int np, int nslots)
{
    __shared__ _Float16 hb[4 * 2048];

    const int tid = threadIdx.x;
    const int wv = tid >> 6;
    const int l  = tid & 63;
    const int lr = l & 31;
    const int hi = l >> 5;

    int xp = hi, yp = 2 + hi;
    asm("v_permlane32_swap_b32 %0, %1" : "+v"(xp), "+v"(yp));
    const int chan = lr + ((xp & 2) ? 32 : 0);
    const int rot = (__builtin_amdgcn_readfirstlane(xp) != 0);

    const float w1r0 = W1[l], w1r1 = W1[64 + l], w1r2 = W1[128 + l];
    const float b1v = b1[l];
    const float b2v0 = b2[lr], b2v1 = b2[32 + lr];

    f16x8 bfr[2][4];
    #pragma unroll
    for (int nf = 0; nf < 2; ++nf)
        #pragma unroll
        for (int ks = 0; ks < 4; ++ks) {
            f16x8 v;
            #pragma unroll
            for (int i = 0; i < 8; ++i)
                v[i] = (_Float16)W2[(ks * 16 + hi * 8 + i) * 64 + nf * 32 + lr];
            bfr[nf][ks] = v;
        }

    f16x2 wk1p[32];
    float bk1v[8];
    #pragma unroll
    for (int o = 0; o < 8; ++o) {
        #pragma unroll
        for (int j = 0; j < 4; ++j)
            wk1p[o * 4 + j] = f16x2{(_Float16)Wk1[o * 8 + 2 * j],
                                    (_Float16)Wk1[o * 8 + 2 * j + 1]};
        bk1v[o] = bk1[o];
    }
    f16x2 wk2p[4];
    #pragma unroll
    for (int j = 0; j < 4; ++j)
        wk2p[j] = f16x2{(_Float16)Wk2[2 * j], (_Float16)Wk2[2 * j + 1]};
    const float bk2v = bk2[0];

    _Float16* hw = hb + wv * 2048;
    const int r7 = lr & 7;

    const int ngrp = (np + 3) >> 2;
    for (int g = blockIdx.x * 4 + wv; g < ngrp; g += nslots) {
        const int gu = __builtin_amdgcn_readfirstlane(g);
        const int p0 = gu * 4;

        #pragma unroll
        for (int pl = 0; pl < 4; ++pl) {
            const float* pp = pos + (size_t)((p0 + pl < np) ? (p0 + pl) : (np - 1)) * 24;
            #pragma unroll
            for (int kk = 0; kk < KNN; ++kk) {
                const int row = pl * 8 + kk;
                float x0 = pp[kk * 3 + 0], x1 = pp[kk * 3 + 1], x2 = pp[kk * 3 + 2];
                float h = fmaf(x2, w1r2, fmaf(x1, w1r1, fmaf(x0, w1r0, b1v)));
                h = fmaxf(h, 0.01f * h);
                hw[row * 64 + (l ^ ((row & 7) << 3))] = (_Float16)h;
            }
        }

        f16x8 a[4];
        #pragma unroll
        for (int ks = 0; ks < 4; ++ks)
            a[ks] = *(const f16x8*)&hw[lr * 64 + (((ks * 2 + hi) ^ r7) << 3)];

        f32x16 acc0, acc1;
        #pragma unroll
        for (int q = 0; q < 16; ++q) { acc0[q] = 0.f; acc1[q] = 0.f; }
        #pragma unroll
        for (int ks = 0; ks < 4; ++ks) {
            acc0 = __builtin_amdgcn_mfma_f32_32x32x16_f16(a[ks], bfr[0][ks], acc0, 0, 0, 0);
            acc1 = __builtin_amdgcn_mfma_f32_32x32x16_f16(a[ks], bfr[1][ks], acc1, 0, 0, 0);
        }
        #pragma unroll
        for (int q = 0; q < 16; ++q) { acc0[q] += b2v0; acc1[q] += b2v1; }

        float pfv[4];
        #pragma unroll
        for (int pl = 0; pl < 4; ++pl) {
            f16x2 x1 = pkrtz(acc0[pl * 4 + 0], acc0[pl * 4 + 1]);
            f16x2 x2 = pkrtz(acc0[pl * 4 + 2], acc0[pl * 4 + 3]);
            f16x2 y1 = pkrtz(acc1[pl * 4 + 0], acc1[pl * 4 + 1]);
            f16x2 y2 = pkrtz(acc1[pl * 4 + 2], acc1[pl * 4 + 3]);
            plswap(x1, y1);
            plswap(x2, y2);
            f16x2 k01 = rot ? y1 : x1;
            f16x2 k23 = rot ? y2 : x2;
            f16x2 k45 = rot ? x1 : y1;
            f16x2 k67 = rot ? x2 : y2;
            float f1[8];
            #pragma unroll
            for (int o = 0; o < 8; ++o) {
                float f = bk1v[o];
                f = __builtin_amdgcn_fdot2(k01, wk1p[o * 4 + 0], f, false);
                f = __builtin_amdgcn_fdot2(k23, wk1p[o * 4 + 1], f, false);
                f = __builtin_amdgcn_fdot2(k45, wk1p[o * 4 + 2], f, false);
                f = __builtin_amdgcn_fdot2(k67, wk1p[o * 4 + 3], f, false);
                f1[o] = fmaxf(f, 0.01f * f);
            }
            float pf = bk2v;
            #pragma unroll
            for (int j = 0; j < 4; ++j)
                pf = __builtin_amdgcn_fdot2(pkrtz(f1[2 * j], f1[2 * j + 1]), wk2p[j], pf, false);
            pfv[pl] = pf;
        }

        const int* pq = pts + (size_t)p0 * 3;
        #pragma unroll
        for (int pl = 0; pl < 4; ++pl) {
            if (p0 + pl < np) {
                int cell = (pq[pl * 3 + 0] * G + pq[pl * 3 + 1]) * G + pq[pl * 3 + 2];
                atomicAdd(&sums[(size_t)cell * 64 + chan], pfv[pl]);
                if (l == 0) atomicAdd(&cnt[cell], 1.0f);
            }
        }
    }
}

// ---------------------------------------------------------------------------
// Kernel 2: fused mean + fp32->fp16 convert into zero-padded 66^3 grid.
// ---------------------------------------------------------------------------
__global__ __launch_bounds__(256) void convert_pad(
    const float* __restrict__ sums, const float* __restrict__ cnt,
    _Float16* __restrict__ gpad)
{
    int t = blockIdx.x * 256 + threadIdx.x;
    if (t >= PAD * PAD * PAD * 8) return;
    int slot = t & 7;
    int cell = t >> 3;
    int x = cell % PAD; int r = cell / PAD; int y = r % PAD; int z = r / PAD;
    f16x8 v;
    #pragma unroll
    for (int i = 0; i < 8; ++i) v[i] = (_Float16)0.f;
    if (x >= 1 && x <= G && y >= 1 && y <= G && z >= 1 && z <= G) {
        int src = ((z - 1) * G + (y - 1)) * G + (x - 1);
        float c = cnt[src];
        float inv = (c > 0.f) ? 1.f / c : 0.f;
        const float4* p = (const float4*)&sums[(size_t)src * 64 + slot * 8];
        float4 a = p[0], b = p[1];
        v = f16x8{(_Float16)(a.x * inv), (_Float16)(a.y * inv), (_Float16)(a.z * inv), (_Float16)(a.w * inv),
                  (_Float16)(b.x * inv), (_Float16)(b.y * inv), (_Float16)(b.z * inv), (_Float16)(b.w * inv)};
    }
    *(f16x8*)&gpad[(size_t)cell * 64 + slot * 8] = v;
}

// ---------------------------------------------------------------------------
// Kernel 3: weight transform OIDHW fp32 -> fp16 B-fragment stream.
// ---------------------------------------------------------------------------
__global__ __launch_bounds__(256) void transform_w_fp16(
    const float* __restrict__ w, _Float16* __restrict__ wT)
{
    int o = blockIdx.x * 256 + threadIdx.x;
    if (o < 27 * 4 * 2 * 64 * 8) {
        int i   = o & 7;
        int l   = (o >> 3) & 63;
        int nf  = (o >> 9) & 1;
        int ks  = (o >> 10) & 3;
        int tap = o >> 12;
        int co = nf * 32 + (l & 31);
        int ci = ks * 16 + (l >> 5) * 8 + i;
        wT[o] = (_Float16)w[(co * 64 + ci) * 27 + tap];
    }
}

// ---------------------------------------------------------------------------
// Kernel 4: implicit-GEMM conv from padded fp16 grid, ci-half-split staging
// via global_load_lds DMA (linear LDS dest, channel-rotation applied on the
// GLOBAL source address). Block = 8x8x8 out tile, halo 10^3 x 32ch = 64 KB
// -> 2 blocks/CU. 4 waves, wave = 4 mt x 2 nf; acc persists across halves.
// OUT_PAD: write padded fp16 (conv1), else dense fp32 to d_out (conv2).
// ---------------------------------------------------------------------------
template<int OUT_PAD>
__global__ __launch_bounds__(256, 2) void conv3d_dma(
    const _Float16* __restrict__ in, const _Float16* __restrict__ wT,
    const float* __restrict__ bias, void* __restrict__ out_)
{
    extern __shared__ ushort tile[];   // 4096 chunks x 16 B (reads use 4000)

    const int lb = blockIdx.x;
    const int bx = (lb & 7) * 64 + (lb >> 3);       // XCD-contiguous z-slabs
    const int X0 = (bx & 7) * 8, Y0 = ((bx >> 3) & 7) * 8, Z0 = (bx >> 6) * 8;
    const int tid = threadIdx.x;
    const int lane = tid & 63;
    const int wv   = tid >> 6;
    const int lr   = lane & 31;
    const int hi   = lane >> 5;

    int base_m[4];
    #pragma unroll
    for (int mt = 0; mt < 4; ++mt)
        base_m[mt] = (2 * wv + (mt >> 1)) * 100 + ((mt & 1) * 4 + (lr >> 3)) * 10 + (lr & 7);

    f32x16 acc[4][2];
    #pragma unroll
    for (int mt = 0; mt < 4; ++mt)
        #pragma unroll
        for (int nf = 0; nf < 2; ++nf)
            #pragma unroll
            for (int q = 0; q < 16; ++q) acc[mt][nf][q] = 0.f;

    const f16x8* wTB = (const f16x8*)wT;

    #pragma unroll 1
    for (int half = 0; half < 2; ++half) {
        if (half) __syncthreads();          // all reads of buffer done

        // ---- stage: 4096 chunks, DMA, no predicates (padded input) ----
        #pragma unroll
        for (int n = 0; n < 16; ++n) {
            const int cw = n * 256 + wv * 64;       // wave-uniform chunk base
            const int c = cw + lane;
            const int vox = c >> 2, t = c & 3;
            const int sg = (t - vox) & 3;           // pre-swizzled source slot
            const int hz = vox / 100, r0 = vox - hz * 100;
            const int hy = r0 / 10, hx = r0 - hy * 10;
            const _Float16* gp = in +
                ((size_t)(((Z0 + hz) * PAD + (Y0 + hy)) * PAD + (X0 + hx)) * 64
                 + half * 32 + sg * 8);
            gload_lds16(gp, (void*)(tile + (size_t)cw * 8));
        }
        asm volatile("s_waitcnt vmcnt(0)" ::: "memory");
        __syncthreads();

        // ---- K-loop: 27 taps x 2 k-slices of this half ----
        #pragma unroll
        for (int dz = 0; dz < 3; ++dz)
        #pragma unroll
        for (int dy = 0; dy < 3; ++dy)
        #pragma unroll
        for (int dx = 0; dx < 3; ++dx) {
            const int tap = (dz * 3 + dy) * 3 + dx;
            const int rowoff = dz * 100 + dy * 10 + dx;
            const f16x8* wB = wTB + tap * 512 + lane;
            f16x8 B0[2], B1[2];
            #pragma unroll
            for (int ksp = 0; ksp < 2; ++ksp) {
                const int ks = half * 2 + ksp;
                B0[ksp] = wB[(ks * 2 + 0) * 64];
                B1[ksp] = wB[(ks * 2 + 1) * 64];
            }
            #pragma unroll
            for (int ksp = 0; ksp < 2; ++ksp) {
                const int c8 = ksp * 2 + hi;
                #pragma unroll
                for (int mt = 0; mt < 4; ++mt) {
                    const int voxr = base_m[mt] + rowoff;
                    f16x8 a = *(const f16x8*)&tile[voxr * 32 + (((c8 + voxr) & 3) << 3)];
                    acc[mt][0] = __builtin_amdgcn_mfma_f32_32x32x16_f16(a, B0[ksp], acc[mt][0], 0, 0, 0);
                    acc[mt][1] = __builtin_amdgcn_mfma_f32_32x32x16_f16(a, B1[ksp], acc[mt][1], 0, 0, 0);
                }
            }
        }
    }

    // ---- epilogue: bias + relu ----
    const float bv0 = bias[lr], bv1 = bias[32 + lr];
    #pragma unroll
    for (int mt = 0; mt < 4; ++mt) {
        #pragma unroll
        for (int r = 0; r < 16; ++r) {
            int row = (r & 3) + 8 * (r >> 2) + 4 * hi;   // C/D: col=lane&31
            int vlw = mt * 32 + row;
            int vz = 2 * wv + (vlw >> 6);
            int rem = vlw & 63;
            int gy = Y0 + (rem >> 3), gx = X0 + (rem & 7), gz = Z0 + vz;
            float v0 = fmaxf(acc[mt][0][r] + bv0, 0.f);
            float v1 = fmaxf(acc[mt][1][r] + bv1, 0.f);
            if (OUT_PAD) {
                size_t off = ((size_t)(((gz + 1) * PAD + (gy + 1)) * PAD + (gx + 1))) * 64 + lr;
                ((_Float16*)out_)[off]      = (_Float16)v0;
                ((_Float16*)out_)[off + 32] = (_Float16)v1;
            } else {
                size_t off = (((size_t)(gz * 64 + gy) * 64 + gx) << 6) + lr;
                ((float*)out_)[off]      = v0;
                ((float*)out_)[off + 32] = v1;
            }
        }
    }
}

// ---------------------------------------------------------------------------
extern "C" void kernel_launch(void* const* d_in, const int* in_sizes, int n_in,
                              void* d_out, int out_size, void* d_ws, size_t ws_size,
                              hipStream_t stream)
{
    const float* pos  = (const float*)d_in[0];
    const int*   pts  = (const int*)  d_in[1];
    const float* W1   = (const float*)d_in[2];
    const float* b1   = (const float*)d_in[3];
    const float* W2   = (const float*)d_in[4];
    const float* b2   = (const float*)d_in[5];
    const float* Wk1  = (const float*)d_in[6];
    const float* bk1  = (const float*)d_in[7];
    const float* Wk2  = (const float*)d_in[8];
    const float* bk2  = (const float*)d_in[9];
    const float* Cw1  = (const float*)d_in[10];
    const float* Cb1  = (const float*)d_in[11];
    const float* Cw2  = (const float*)d_in[12];
    const float* Cb2  = (const float*)d_in[13];

    float* out = (float*)d_out;                     // fp32 sums, then final out
    char*  ws  = (char*)d_ws;
    const size_t PADB = (size_t)PAD * PAD * PAD * 64 * 2;   // 36,799,488 B
    _Float16* gpad  = (_Float16*)ws;                // conv1 input (padded fp16)
    _Float16* c1pad = (_Float16*)(ws + PADB);       // conv1 output (padded fp16)
    float*    cntb  = (float*)(ws + 2 * PADB);      // 1 MB counts
    _Float16* wT1   = (_Float16*)(ws + 2 * PADB + 1048576);
    _Float16* wT2   = (_Float16*)(ws + 2 * PADB + 1048576 + 221184);

    const int np = in_sizes[0] / 24;

    (void)hipMemsetAsync(out,   0, 67108864, stream);   // sums accumulate here
    (void)hipMemsetAsync(cntb,  0, 1048576, stream);
    (void)hipMemsetAsync(c1pad, 0, PADB, stream);       // borders must be zero

    transform_w_fp16<<<432, 256, 0, stream>>>(Cw1, wT1);
    transform_w_fp16<<<432, 256, 0, stream>>>(Cw2, wT2);

    const int nblk = 2048;
    point_mlp_scatter<<<nblk, 256, 0, stream>>>(
        pos, pts, W1, b1, W2, b2, Wk1, bk1, Wk2, bk2, out, cntb, np, nblk * 4);

    const int padthr = PAD * PAD * PAD * 8;
    convert_pad<<<(padthr + 255) / 256, 256, 0, stream>>>(out, cntb, gpad);

    conv3d_dma<1><<<512, 256, 65536, stream>>>(gpad, wT1, Cb1, (void*)c1pad);
    conv3d_dma<0><<<512, 256, 65536, stream>>>(c1pad, wT2, Cb2, (void*)out);
}

// Round 9
// 382.745 us; speedup vs baseline: 1.3672x; 1.3672x over previous
//
#include <hip/hip_runtime.h>
#include <hip/hip_fp16.h>

#define G 64
#define KNN 8

typedef _Float16 f16x2 __attribute__((ext_vector_type(2)));
typedef _Float16 f16x8 __attribute__((ext_vector_type(8)));
typedef float f32x16 __attribute__((ext_vector_type(16)));

static __device__ __forceinline__ f16x2 pkrtz(float a, float b) {
    return __builtin_bit_cast(f16x2, __builtin_amdgcn_cvt_pkrtz(a, b));
}
static __device__ __forceinline__ void plswap(f16x2& a, f16x2& b) {
    int ai = __builtin_bit_cast(int, a), bi = __builtin_bit_cast(int, b);
    asm("v_permlane32_swap_b32 %0, %1" : "+v"(ai), "+v"(bi));
    a = __builtin_bit_cast(f16x2, ai);
    b = __builtin_bit_cast(f16x2, bi);
}

// ---------------------------------------------------------------------------
// Kernel 1: per-point MLP + scatter (unchanged, passing since round 6).
// ---------------------------------------------------------------------------
__global__ __launch_bounds__(256) void point_mlp_scatter(
    const float* __restrict__ pos, const int* __restrict__ pts,
    const float* __restrict__ W1, const float* __restrict__ b1,
    const float* __restrict__ W2, const float* __restrict__ b2,
    const float* __restrict__ Wk1, const float* __restrict__ bk1,
    const float* __restrict__ Wk2, const float* __restrict__ bk2,
    float* __restrict__ sums, float* __restrict__ cnt, int np, int nslots)
{
    __shared__ _Float16 hb[4 * 2048];

    const int tid = threadIdx.x;
    const int wv = tid >> 6;
    const int l  = tid & 63;
    const int lr = l & 31;
    const int hi = l >> 5;

    int xp = hi, yp = 2 + hi;
    asm("v_permlane32_swap_b32 %0, %1" : "+v"(xp), "+v"(yp));
    const int chan = lr + ((xp & 2) ? 32 : 0);
    const int rot = (__builtin_amdgcn_readfirstlane(xp) != 0);

    const float w1r0 = W1[l], w1r1 = W1[64 + l], w1r2 = W1[128 + l];
    const float b1v = b1[l];
    const float b2v0 = b2[lr], b2v1 = b2[32 + lr];

    f16x8 bfr[2][4];
    #pragma unroll
    for (int nf = 0; nf < 2; ++nf)
        #pragma unroll
        for (int ks = 0; ks < 4; ++ks) {
            f16x8 v;
            #pragma unroll
            for (int i = 0; i < 8; ++i)
                v[i] = (_Float16)W2[(ks * 16 + hi * 8 + i) * 64 + nf * 32 + lr];
            bfr[nf][ks] = v;
        }

    f16x2 wk1p[32];
    float bk1v[8];
    #pragma unroll
    for (int o = 0; o < 8; ++o) {
        #pragma unroll
        for (int j = 0; j < 4; ++j)
            wk1p[o * 4 + j] = f16x2{(_Float16)Wk1[o * 8 + 2 * j],
                                    (_Float16)Wk1[o * 8 + 2 * j + 1]};
        bk1v[o] = bk1[o];
    }
    f16x2 wk2p[4];
    #pragma unroll
    for (int j = 0; j < 4; ++j)
        wk2p[j] = f16x2{(_Float16)Wk2[2 * j], (_Float16)Wk2[2 * j + 1]};
    const float bk2v = bk2[0];

    _Float16* hw = hb + wv * 2048;
    const int r7 = lr & 7;

    const int ngrp = (np + 3) >> 2;
    for (int g = blockIdx.x * 4 + wv; g < ngrp; g += nslots) {
        const int gu = __builtin_amdgcn_readfirstlane(g);
        const int p0 = gu * 4;

        #pragma unroll
        for (int pl = 0; pl < 4; ++pl) {
            const float* pp = pos + (size_t)((p0 + pl < np) ? (p0 + pl) : (np - 1)) * 24;
            #pragma unroll
            for (int kk = 0; kk < KNN; ++kk) {
                const int row = pl * 8 + kk;
                float x0 = pp[kk * 3 + 0], x1 = pp[kk * 3 + 1], x2 = pp[kk * 3 + 2];
                float h = fmaf(x2, w1r2, fmaf(x1, w1r1, fmaf(x0, w1r0, b1v)));
                h = fmaxf(h, 0.01f * h);
                hw[row * 64 + (l ^ ((row & 7) << 3))] = (_Float16)h;
            }
        }

        f16x8 a[4];
        #pragma unroll
        for (int ks = 0; ks < 4; ++ks)
            a[ks] = *(const f16x8*)&hw[lr * 64 + (((ks * 2 + hi) ^ r7) << 3)];

        f32x16 acc0, acc1;
        #pragma unroll
        for (int q = 0; q < 16; ++q) { acc0[q] = 0.f; acc1[q] = 0.f; }
        #pragma unroll
        for (int ks = 0; ks < 4; ++ks) {
            acc0 = __builtin_amdgcn_mfma_f32_32x32x16_f16(a[ks], bfr[0][ks], acc0, 0, 0, 0);
            acc1 = __builtin_amdgcn_mfma_f32_32x32x16_f16(a[ks], bfr[1][ks], acc1, 0, 0, 0);
        }
        #pragma unroll
        for (int q = 0; q < 16; ++q) { acc0[q] += b2v0; acc1[q] += b2v1; }

        float pfv[4];
        #pragma unroll
        for (int pl = 0; pl < 4; ++pl) {
            f16x2 x1 = pkrtz(acc0[pl * 4 + 0], acc0[pl * 4 + 1]);
            f16x2 x2 = pkrtz(acc0[pl * 4 + 2], acc0[pl * 4 + 3]);
            f16x2 y1 = pkrtz(acc1[pl * 4 + 0], acc1[pl * 4 + 1]);
            f16x2 y2 = pkrtz(acc1[pl * 4 + 2], acc1[pl * 4 + 3]);
            plswap(x1, y1);
            plswap(x2, y2);
            f16x2 k01 = rot ? y1 : x1;
            f16x2 k23 = rot ? y2 : x2;
            f16x2 k45 = rot ? x1 : y1;
            f16x2 k67 = rot ? x2 : y2;
            float f1[8];
            #pragma unroll
            for (int o = 0; o < 8; ++o) {
                float f = bk1v[o];
                f = __builtin_amdgcn_fdot2(k01, wk1p[o * 4 + 0], f, false);
                f = __builtin_amdgcn_fdot2(k23, wk1p[o * 4 + 1], f, false);
                f = __builtin_amdgcn_fdot2(k45, wk1p[o * 4 + 2], f, false);
                f = __builtin_amdgcn_fdot2(k67, wk1p[o * 4 + 3], f, false);
                f1[o] = fmaxf(f, 0.01f * f);
            }
            float pf = bk2v;
            #pragma unroll
            for (int j = 0; j < 4; ++j)
                pf = __builtin_amdgcn_fdot2(pkrtz(f1[2 * j], f1[2 * j + 1]), wk2p[j], pf, false);
            pfv[pl] = pf;
        }

        const int* pq = pts + (size_t)p0 * 3;
        #pragma unroll
        for (int pl = 0; pl < 4; ++pl) {
            if (p0 + pl < np) {
                int cell = (pq[pl * 3 + 0] * G + pq[pl * 3 + 1]) * G + pq[pl * 3 + 2];
                atomicAdd(&sums[(size_t)cell * 64 + chan], pfv[pl]);
                if (l == 0) atomicAdd(&cnt[cell], 1.0f);
            }
        }
    }
}

// ---------------------------------------------------------------------------
// Kernel 2: mean + fp32->fp16 convert, dense 64^3 grid.
// ---------------------------------------------------------------------------
__global__ __launch_bounds__(256) void convert_dense(
    const float* __restrict__ sums, const float* __restrict__ cnt,
    _Float16* __restrict__ g16)
{
    int t = blockIdx.x * 256 + threadIdx.x;      // 64^3 cells x 8 slots
    int cell = t >> 3, slot = t & 7;
    float c = cnt[cell];
    float inv = (c > 0.f) ? 1.f / c : 0.f;
    const float4* p = (const float4*)&sums[(size_t)cell * 64 + slot * 8];
    float4 a = p[0], b = p[1];
    f16x8 v = f16x8{(_Float16)(a.x * inv), (_Float16)(a.y * inv),
                    (_Float16)(a.z * inv), (_Float16)(a.w * inv),
                    (_Float16)(b.x * inv), (_Float16)(b.y * inv),
                    (_Float16)(b.z * inv), (_Float16)(b.w * inv)};
    *(f16x8*)&g16[(size_t)cell * 64 + slot * 8] = v;
}

// ---------------------------------------------------------------------------
// Kernel 3: weight transform OIDHW fp32 -> fp16 B-fragment stream.
// ---------------------------------------------------------------------------
__global__ __launch_bounds__(256) void transform_w_fp16(
    const float* __restrict__ w, _Float16* __restrict__ wT)
{
    int o = blockIdx.x * 256 + threadIdx.x;
    if (o < 27 * 4 * 2 * 64 * 8) {
        int i   = o & 7;
        int l   = (o >> 3) & 63;
        int nf  = (o >> 9) & 1;
        int ks  = (o >> 10) & 3;
        int tap = o >> 12;
        int co = nf * 32 + (l & 31);
        int ci = ks * 16 + (l >> 5) * 8 + i;
        wT[o] = (_Float16)w[(co * 64 + ci) * 27 + tap];
    }
}

// ---------------------------------------------------------------------------
// Kernel 4: implicit-GEMM conv, ci-half-split LDS staging (r6 structure).
// Block = 8x8x8 out tile; halo 10^3 x 32ch fp16 = 64 KB -> 2 blocks/CU.
// 4 waves, wave = 4 mt x 2 nf; K-loop runs twice (ci halves), acc persists.
// LDS slot = ((vox>>1)+t)&3: uniform bank spread WITHIN each SIMD-32 pass
// (the r6 (vox+t)&3 variant left 2 slots x 8 lanes per half => 2x LDS time).
// OUT_F32: conv2 writes fp32 dense to d_out; else fp16 dense.
// ---------------------------------------------------------------------------
template<int OUT_F32>
__global__ __launch_bounds__(256, 2) void conv3d_mfma_h(
    const _Float16* __restrict__ in, const _Float16* __restrict__ wT,
    const float* __restrict__ bias, void* __restrict__ out_)
{
    extern __shared__ ushort tile[];   // [1000 vox][32 ch], slot-rotated

    const int lb = blockIdx.x;
    const int bx = (lb & 7) * 64 + (lb >> 3);       // XCD-contiguous z-slabs
    const int X0 = (bx & 7) * 8, Y0 = ((bx >> 3) & 7) * 8, Z0 = (bx >> 6) * 8;
    const int tid = threadIdx.x;
    const int lane = tid & 63;
    const int wv   = tid >> 6;
    const int lr   = lane & 31;
    const int hi   = lane >> 5;

    int base_m[4];
    #pragma unroll
    for (int mt = 0; mt < 4; ++mt)
        base_m[mt] = (2 * wv + (mt >> 1)) * 100 + ((mt & 1) * 4 + (lr >> 3)) * 10 + (lr & 7);

    f32x16 acc[4][2];
    #pragma unroll
    for (int mt = 0; mt < 4; ++mt)
        #pragma unroll
        for (int nf = 0; nf < 2; ++nf)
            #pragma unroll
            for (int q = 0; q < 16; ++q) acc[mt][nf][q] = 0.f;

    const f16x8* wTB = (const f16x8*)wT;

    #pragma unroll 1
    for (int half = 0; half < 2; ++half) {
        if (half) __syncthreads();              // all reads of buffer done

        // ---- stage halo (32 ch of this half): chunk = (vox, 16B slot) ----
        for (int c = tid; c < 4000; c += 256) {
            int vox = c >> 2, t = c & 3;
            int hz = vox / 100, r0 = vox - hz * 100;
            int hy = r0 / 10, hx = r0 - hy * 10;
            int gz = Z0 + hz - 1, gy = Y0 + hy - 1, gx = X0 + hx - 1;
            int dst = vox * 32 + ((((vox >> 1) + t) & 3) << 3);
            bool ok = ((unsigned)gz < 64u) && ((unsigned)gy < 64u) && ((unsigned)gx < 64u);
            uint4 v = make_uint4(0u, 0u, 0u, 0u);
            if (ok) v = *(const uint4*)((const ushort*)in +
                    ((size_t)((gz * 64 + gy) * 64 + gx) * 64 + half * 32 + t * 8));
            *(uint4*)&tile[dst] = v;
        }
        __syncthreads();

        // ---- K-loop over 27 taps x 2 k-slices of this half ----
        #pragma unroll
        for (int dz = 0; dz < 3; ++dz)
        #pragma unroll
        for (int dy = 0; dy < 3; ++dy)
        #pragma unroll
        for (int dx = 0; dx < 3; ++dx) {
            const int tap = (dz * 3 + dy) * 3 + dx;
            const int rowoff = dz * 100 + dy * 10 + dx;
            const f16x8* wB = wTB + tap * 512 + lane;
            f16x8 B0[2], B1[2];
            #pragma unroll
            for (int ksp = 0; ksp < 2; ++ksp) {
                const int ks = half * 2 + ksp;
                B0[ksp] = wB[(ks * 2 + 0) * 64];
                B1[ksp] = wB[(ks * 2 + 1) * 64];
            }
            #pragma unroll
            for (int ksp = 0; ksp < 2; ++ksp) {
                const int c8 = ksp * 2 + hi;
                #pragma unroll
                for (int mt = 0; mt < 4; ++mt) {
                    const int voxr = base_m[mt] + rowoff;
                    f16x8 a = *(const f16x8*)&tile[voxr * 32 + ((((voxr >> 1) + c8) & 3) << 3)];
                    acc[mt][0] = __builtin_amdgcn_mfma_f32_32x32x16_f16(a, B0[ksp], acc[mt][0], 0, 0, 0);
                    acc[mt][1] = __builtin_amdgcn_mfma_f32_32x32x16_f16(a, B1[ksp], acc[mt][1], 0, 0, 0);
                }
            }
        }
    }

    // ---- epilogue: bias + relu ----
    const float bv0 = bias[lr], bv1 = bias[32 + lr];
    #pragma unroll
    for (int mt = 0; mt < 4; ++mt) {
        #pragma unroll
        for (int r = 0; r < 16; ++r) {
            int row = (r & 3) + 8 * (r >> 2) + 4 * hi;   // C/D: col=lane&31
            int vlw = mt * 32 + row;
            int vz = 2 * wv + (vlw >> 6);
            int rem = vlw & 63;
            int gy = Y0 + (rem >> 3), gx = X0 + (rem & 7), gz = Z0 + vz;
            size_t off = (((size_t)(gz * 64 + gy) * 64 + gx) << 6) + lr;
            float v0 = fmaxf(acc[mt][0][r] + bv0, 0.f);
            float v1 = fmaxf(acc[mt][1][r] + bv1, 0.f);
            if (OUT_F32) {
                ((float*)out_)[off]      = v0;
                ((float*)out_)[off + 32] = v1;
            } else {
                ((_Float16*)out_)[off]      = (_Float16)v0;
                ((_Float16*)out_)[off + 32] = (_Float16)v1;
            }
        }
    }
}

// ---------------------------------------------------------------------------
extern "C" void kernel_launch(void* const* d_in, const int* in_sizes, int n_in,
                              void* d_out, int out_size, void* d_ws, size_t ws_size,
                              hipStream_t stream)
{
    const float* pos  = (const float*)d_in[0];
    const int*   pts  = (const int*)  d_in[1];
    const float* W1   = (const float*)d_in[2];
    const float* b1   = (const float*)d_in[3];
    const float* W2   = (const float*)d_in[4];
    const float* b2   = (const float*)d_in[5];
    const float* Wk1  = (const float*)d_in[6];
    const float* bk1  = (const float*)d_in[7];
    const float* Wk2  = (const float*)d_in[8];
    const float* bk2  = (const float*)d_in[9];
    const float* Cw1  = (const float*)d_in[10];
    const float* Cb1  = (const float*)d_in[11];
    const float* Cw2  = (const float*)d_in[12];
    const float* Cb2  = (const float*)d_in[13];

    float* out = (float*)d_out;                     // fp32 sums, then final out
    char*  ws  = (char*)d_ws;
    _Float16* g16  = (_Float16*)ws;                 // [0, 32M): mean grid fp16
    _Float16* c1d  = (_Float16*)(ws + 33554432);    // [32M, 64M): conv1 out fp16
    float*    cntb = (float*)(ws + 67108864);       // 1 MB counts
    _Float16* wT1  = (_Float16*)(ws + 68157440);    // 221184 B
    _Float16* wT2  = (_Float16*)(ws + 68378624);    // 221184 B

    const int np = in_sizes[0] / 24;

    (void)hipMemsetAsync(out,  0, 67108864, stream);    // sums accumulate here
    (void)hipMemsetAsync(cntb, 0, 1048576, stream);

    transform_w_fp16<<<432, 256, 0, stream>>>(Cw1, wT1);
    transform_w_fp16<<<432, 256, 0, stream>>>(Cw2, wT2);

    const int nblk = 2048;
    point_mlp_scatter<<<nblk, 256, 0, stream>>>(
        pos, pts, W1, b1, W2, b2, Wk1, bk1, Wk2, bk2, out, cntb, np, nblk * 4);

    convert_dense<<<8192, 256, 0, stream>>>(out, cntb, g16);

    conv3d_mfma_h<0><<<512, 256, 64000, stream>>>(g16, wT1, Cb1, (void*)c1d);
    conv3d_mfma_h<1><<<512, 256, 64000, stream>>>(c1d, wT2, Cb2, (void*)out);
}

// Round 10
// 285.589 us; speedup vs baseline: 1.8323x; 1.3402x over previous
//
#include <hip/hip_runtime.h>
#include <hip/hip_fp16.h>

#define G 64
#define KNN 8

typedef _Float16 f16x2 __attribute__((ext_vector_type(2)));
typedef _Float16 f16x8 __attribute__((ext_vector_type(8)));
typedef float f32x16 __attribute__((ext_vector_type(16)));

static __device__ __forceinline__ f16x2 pkrtz(float a, float b) {
    return __builtin_bit_cast(f16x2, __builtin_amdgcn_cvt_pkrtz(a, b));
}
static __device__ __forceinline__ void plswap(f16x2& a, f16x2& b) {
    int ai = __builtin_bit_cast(int, a), bi = __builtin_bit_cast(int, b);
    asm("v_permlane32_swap_b32 %0, %1" : "+v"(ai), "+v"(bi));
    a = __builtin_bit_cast(f16x2, ai);
    b = __builtin_bit_cast(f16x2, bi);
}

// ---------------------------------------------------------------------------
// Kernel 1: per-point MLP + scatter (unchanged, passing since round 6).
// ---------------------------------------------------------------------------
__global__ __launch_bounds__(256) void point_mlp_scatter(
    const float* __restrict__ pos, const int* __restrict__ pts,
    const float* __restrict__ W1, const float* __restrict__ b1,
    const float* __restrict__ W2, const float* __restrict__ b2,
    const float* __restrict__ Wk1, const float* __restrict__ bk1,
    const float* __restrict__ Wk2, const float* __restrict__ bk2,
    float* __restrict__ sums, float* __restrict__ cnt, int np, int nslots)
{
    __shared__ _Float16 hb[4 * 2048];

    const int tid = threadIdx.x;
    const int wv = tid >> 6;
    const int l  = tid & 63;
    const int lr = l & 31;
    const int hi = l >> 5;

    int xp = hi, yp = 2 + hi;
    asm("v_permlane32_swap_b32 %0, %1" : "+v"(xp), "+v"(yp));
    const int chan = lr + ((xp & 2) ? 32 : 0);
    const int rot = (__builtin_amdgcn_readfirstlane(xp) != 0);

    const float w1r0 = W1[l], w1r1 = W1[64 + l], w1r2 = W1[128 + l];
    const float b1v = b1[l];
    const float b2v0 = b2[lr], b2v1 = b2[32 + lr];

    f16x8 bfr[2][4];
    #pragma unroll
    for (int nf = 0; nf < 2; ++nf)
        #pragma unroll
        for (int ks = 0; ks < 4; ++ks) {
            f16x8 v;
            #pragma unroll
            for (int i = 0; i < 8; ++i)
                v[i] = (_Float16)W2[(ks * 16 + hi * 8 + i) * 64 + nf * 32 + lr];
            bfr[nf][ks] = v;
        }

    f16x2 wk1p[32];
    float bk1v[8];
    #pragma unroll
    for (int o = 0; o < 8; ++o) {
        #pragma unroll
        for (int j = 0; j < 4; ++j)
            wk1p[o * 4 + j] = f16x2{(_Float16)Wk1[o * 8 + 2 * j],
                                    (_Float16)Wk1[o * 8 + 2 * j + 1]};
        bk1v[o] = bk1[o];
    }
    f16x2 wk2p[4];
    #pragma unroll
    for (int j = 0; j < 4; ++j)
        wk2p[j] = f16x2{(_Float16)Wk2[2 * j], (_Float16)Wk2[2 * j + 1]};
    const float bk2v = bk2[0];

    _Float16* hw = hb + wv * 2048;
    const int r7 = lr & 7;

    const int ngrp = (np + 3) >> 2;
    for (int g = blockIdx.x * 4 + wv; g < ngrp; g += nslots) {
        const int gu = __builtin_amdgcn_readfirstlane(g);
        const int p0 = gu * 4;

        #pragma unroll
        for (int pl = 0; pl < 4; ++pl) {
            const float* pp = pos + (size_t)((p0 + pl < np) ? (p0 + pl) : (np - 1)) * 24;
            #pragma unroll
            for (int kk = 0; kk < KNN; ++kk) {
                const int row = pl * 8 + kk;
                float x0 = pp[kk * 3 + 0], x1 = pp[kk * 3 + 1], x2 = pp[kk * 3 + 2];
                float h = fmaf(x2, w1r2, fmaf(x1, w1r1, fmaf(x0, w1r0, b1v)));
                h = fmaxf(h, 0.01f * h);
                hw[row * 64 + (l ^ ((row & 7) << 3))] = (_Float16)h;
            }
        }

        f16x8 a[4];
        #pragma unroll
        for (int ks = 0; ks < 4; ++ks)
            a[ks] = *(const f16x8*)&hw[lr * 64 + (((ks * 2 + hi) ^ r7) << 3)];

        f32x16 acc0, acc1;
        #pragma unroll
        for (int q = 0; q < 16; ++q) { acc0[q] = 0.f; acc1[q] = 0.f; }
        #pragma unroll
        for (int ks = 0; ks < 4; ++ks) {
            acc0 = __builtin_amdgcn_mfma_f32_32x32x16_f16(a[ks], bfr[0][ks], acc0, 0, 0, 0);
            acc1 = __builtin_amdgcn_mfma_f32_32x32x16_f16(a[ks], bfr[1][ks], acc1, 0, 0, 0);
        }
        #pragma unroll
        for (int q = 0; q < 16; ++q) { acc0[q] += b2v0; acc1[q] += b2v1; }

        float pfv[4];
        #pragma unroll
        for (int pl = 0; pl < 4; ++pl) {
            f16x2 x1 = pkrtz(acc0[pl * 4 + 0], acc0[pl * 4 + 1]);
            f16x2 x2 = pkrtz(acc0[pl * 4 + 2], acc0[pl * 4 + 3]);
            f16x2 y1 = pkrtz(acc1[pl * 4 + 0], acc1[pl * 4 + 1]);
            f16x2 y2 = pkrtz(acc1[pl * 4 + 2], acc1[pl * 4 + 3]);
            plswap(x1, y1);
            plswap(x2, y2);
            f16x2 k01 = rot ? y1 : x1;
            f16x2 k23 = rot ? y2 : x2;
            f16x2 k45 = rot ? x1 : y1;
            f16x2 k67 = rot ? x2 : y2;
            float f1[8];
            #pragma unroll
            for (int o = 0; o < 8; ++o) {
                float f = bk1v[o];
                f = __builtin_amdgcn_fdot2(k01, wk1p[o * 4 + 0], f, false);
                f = __builtin_amdgcn_fdot2(k23, wk1p[o * 4 + 1], f, false);
                f = __builtin_amdgcn_fdot2(k45, wk1p[o * 4 + 2], f, false);
                f = __builtin_amdgcn_fdot2(k67, wk1p[o * 4 + 3], f, false);
                f1[o] = fmaxf(f, 0.01f * f);
            }
            float pf = bk2v;
            #pragma unroll
            for (int j = 0; j < 4; ++j)
                pf = __builtin_amdgcn_fdot2(pkrtz(f1[2 * j], f1[2 * j + 1]), wk2p[j], pf, false);
            pfv[pl] = pf;
        }

        const int* pq = pts + (size_t)p0 * 3;
        #pragma unroll
        for (int pl = 0; pl < 4; ++pl) {
            if (p0 + pl < np) {
                int cell = (pq[pl * 3 + 0] * G + pq[pl * 3 + 1]) * G + pq[pl * 3 + 2];
                atomicAdd(&sums[(size_t)cell * 64 + chan], pfv[pl]);
                if (l == 0) atomicAdd(&cnt[cell], 1.0f);
            }
        }
    }
}

// ---------------------------------------------------------------------------
// Kernel 3: weight transform OIDHW fp32 -> fp16 B-fragment stream.
// ---------------------------------------------------------------------------
__global__ __launch_bounds__(256) void transform_w_fp16(
    const float* __restrict__ w, _Float16* __restrict__ wT)
{
    int o = blockIdx.x * 256 + threadIdx.x;
    if (o < 27 * 4 * 2 * 64 * 8) {
        int i   = o & 7;
        int l   = (o >> 3) & 63;
        int nf  = (o >> 9) & 1;
        int ks  = (o >> 10) & 3;
        int tap = o >> 12;
        int co = nf * 32 + (l & 31);
        int ci = ks * 16 + (l >> 5) * 8 + i;
        wT[o] = (_Float16)w[(co * 64 + ci) * 27 + tap];
    }
}

// ---------------------------------------------------------------------------
// Kernel 4: implicit-GEMM conv (r6 structure, single-pass staging).
// Block = 8x8x8 out tile; halo 10^3 x 32ch fp16 = 64 KB -> 2 blocks/CU.
// Staging loads the FULL 128-B channel line once: ci 0..31 -> LDS now,
// ci 32..63 -> 16 regs (fp16), written to LDS after half-0's K-loop.
// 4 waves, wave = 4 mt x 2 nf; acc persists across halves. Swizzles = r6.
// CONV1: input fp32 sums normalized by cnt (mean fused), out fp16 dense.
// Else: input fp16 dense, out fp32 to d_out.
// ---------------------------------------------------------------------------
template<int CONV1>
__global__ __launch_bounds__(256, 2) void conv3d_mfma_p(
    const void* __restrict__ in_, const float* __restrict__ cntp,
    const _Float16* __restrict__ wT, const float* __restrict__ bias,
    void* __restrict__ out_)
{
    extern __shared__ ushort tile[];   // [1000 vox][32 ch], slot-rotated

    const int lb = blockIdx.x;
    const int bx = (lb & 7) * 64 + (lb >> 3);       // XCD-contiguous z-slabs
    const int X0 = (bx & 7) * 8, Y0 = ((bx >> 3) & 7) * 8, Z0 = (bx >> 6) * 8;
    const int tid = threadIdx.x;
    const int lane = tid & 63;
    const int wv   = tid >> 6;
    const int lr   = lane & 31;
    const int hi   = lane >> 5;

    int base_m[4];
    #pragma unroll
    for (int mt = 0; mt < 4; ++mt)
        base_m[mt] = (2 * wv + (mt >> 1)) * 100 + ((mt & 1) * 4 + (lr >> 3)) * 10 + (lr & 7);

    f32x16 acc[4][2];
    #pragma unroll
    for (int mt = 0; mt < 4; ++mt)
        #pragma unroll
        for (int nf = 0; nf < 2; ++nf)
            #pragma unroll
            for (int q = 0; q < 16; ++q) acc[mt][nf][q] = 0.f;

    const f16x8* wTB = (const f16x8*)wT;

    // ---- single-pass staging: h0 -> LDS, h1 -> regs ----
    uint4 h1r[16];
    #pragma unroll
    for (int n = 0; n < 16; ++n) {
        const int c = n * 256 + tid;
        const int vox = c >> 2, t = c & 3;
        const int hz = vox / 100, r0 = vox - hz * 100;
        const int hy = r0 / 10, hx = r0 - hy * 10;
        const int gz = Z0 + hz - 1, gy = Y0 + hy - 1, gx = X0 + hx - 1;
        const bool act = (c < 4000);
        const bool ok = act && ((unsigned)gz < 64u) && ((unsigned)gy < 64u) && ((unsigned)gx < 64u);
        uint4 v0 = make_uint4(0u, 0u, 0u, 0u);
        uint4 v1 = make_uint4(0u, 0u, 0u, 0u);
        if (CONV1) {
            if (ok) {
                const int cell = (gz * 64 + gy) * 64 + gx;
                const float cv = cntp[cell];
                const float inv = (cv > 0.f) ? 1.f / cv : 0.f;
                const float4* p = (const float4*)((const float*)in_ + ((size_t)cell * 64 + t * 8));
                float4 a = p[0], b = p[1];       // ch t*8 .. t*8+7
                float4 a1 = p[8], b1 = p[9];     // + 32 ch
                v0 = __builtin_bit_cast(uint4, f16x8{
                    (_Float16)(a.x * inv), (_Float16)(a.y * inv),
                    (_Float16)(a.z * inv), (_Float16)(a.w * inv),
                    (_Float16)(b.x * inv), (_Float16)(b.y * inv),
                    (_Float16)(b.z * inv), (_Float16)(b.w * inv)});
                v1 = __builtin_bit_cast(uint4, f16x8{
                    (_Float16)(a1.x * inv), (_Float16)(a1.y * inv),
                    (_Float16)(a1.z * inv), (_Float16)(a1.w * inv),
                    (_Float16)(b1.x * inv), (_Float16)(b1.y * inv),
                    (_Float16)(b1.z * inv), (_Float16)(b1.w * inv)});
            }
        } else {
            if (ok) {
                const ushort* q = (const ushort*)in_ +
                    ((size_t)((gz * 64 + gy) * 64 + gx) * 64 + t * 8);
                v0 = *(const uint4*)q;
                v1 = *(const uint4*)(q + 32);
            }
        }
        const int dst = vox * 32 + (((t + vox) & 3) << 3);
        if (act) *(uint4*)&tile[dst] = v0;
        h1r[n] = v1;
    }
    __syncthreads();

    // ---- K-loop over 27 taps x 2 k-slices, per half ----
    auto kloop = [&](int half) {
        #pragma unroll
        for (int dz = 0; dz < 3; ++dz)
        #pragma unroll
        for (int dy = 0; dy < 3; ++dy)
        #pragma unroll
        for (int dx = 0; dx < 3; ++dx) {
            const int tap = (dz * 3 + dy) * 3 + dx;
            const int rowoff = dz * 100 + dy * 10 + dx;
            const f16x8* wB = wTB + tap * 512 + lane;
            f16x8 B0[2], B1[2];
            #pragma unroll
            for (int ksp = 0; ksp < 2; ++ksp) {
                const int ks = half * 2 + ksp;
                B0[ksp] = wB[(ks * 2 + 0) * 64];
                B1[ksp] = wB[(ks * 2 + 1) * 64];
            }
            #pragma unroll
            for (int ksp = 0; ksp < 2; ++ksp) {
                const int c8 = ksp * 2 + hi;
                #pragma unroll
                for (int mt = 0; mt < 4; ++mt) {
                    const int voxr = base_m[mt] + rowoff;
                    f16x8 a = *(const f16x8*)&tile[voxr * 32 + (((c8 + voxr) & 3) << 3)];
                    acc[mt][0] = __builtin_amdgcn_mfma_f32_32x32x16_f16(a, B0[ksp], acc[mt][0], 0, 0, 0);
                    acc[mt][1] = __builtin_amdgcn_mfma_f32_32x32x16_f16(a, B1[ksp], acc[mt][1], 0, 0, 0);
                }
            }
        }
    };

    kloop(0);
    __syncthreads();                    // half-0 reads done

    // ---- write h1 from regs (no global traffic) ----
    #pragma unroll
    for (int n = 0; n < 16; ++n) {
        const int c = n * 256 + tid;
        if (c < 4000) {
            const int vox = c >> 2, t = c & 3;
            const int dst = vox * 32 + (((t + vox) & 3) << 3);
            *(uint4*)&tile[dst] = h1r[n];
        }
    }
    __syncthreads();

    kloop(1);

    // ---- epilogue: bias + relu ----
    const float bv0 = bias[lr], bv1 = bias[32 + lr];
    #pragma unroll
    for (int mt = 0; mt < 4; ++mt) {
        #pragma unroll
        for (int r = 0; r < 16; ++r) {
            int row = (r & 3) + 8 * (r >> 2) + 4 * hi;   // C/D: col=lane&31
            int vlw = mt * 32 + row;
            int vz = 2 * wv + (vlw >> 6);
            int rem = vlw & 63;
            int gy = Y0 + (rem >> 3), gx = X0 + (rem & 7), gz = Z0 + vz;
            size_t off = (((size_t)(gz * 64 + gy) * 64 + gx) << 6) + lr;
            float v0 = fmaxf(acc[mt][0][r] + bv0, 0.f);
            float v1 = fmaxf(acc[mt][1][r] + bv1, 0.f);
            if (CONV1) {
                ((_Float16*)out_)[off]      = (_Float16)v0;
                ((_Float16*)out_)[off + 32] = (_Float16)v1;
            } else {
                ((float*)out_)[off]      = v0;
                ((float*)out_)[off + 32] = v1;
            }
        }
    }
}

// ---------------------------------------------------------------------------
extern "C" void kernel_launch(void* const* d_in, const int* in_sizes, int n_in,
                              void* d_out, int out_size, void* d_ws, size_t ws_size,
                              hipStream_t stream)
{
    const float* pos  = (const float*)d_in[0];
    const int*   pts  = (const int*)  d_in[1];
    const float* W1   = (const float*)d_in[2];
    const float* b1   = (const float*)d_in[3];
    const float* W2   = (const float*)d_in[4];
    const float* b2   = (const float*)d_in[5];
    const float* Wk1  = (const float*)d_in[6];
    const float* bk1  = (const float*)d_in[7];
    const float* Wk2  = (const float*)d_in[8];
    const float* bk2  = (const float*)d_in[9];
    const float* Cw1  = (const float*)d_in[10];
    const float* Cb1  = (const float*)d_in[11];
    const float* Cw2  = (const float*)d_in[12];
    const float* Cb2  = (const float*)d_in[13];

    float* out = (float*)d_out;                     // fp32 sums, then final out
    char*  ws  = (char*)d_ws;
    _Float16* c1d  = (_Float16*)ws;                 // [0, 32M): conv1 out fp16 dense
    float*    cntb = (float*)(ws + 33554432);       // 1 MB counts
    _Float16* wT1  = (_Float16*)(ws + 34603008);    // 221184 B
    _Float16* wT2  = (_Float16*)(ws + 34824192);    // 221184 B

    const int np = in_sizes[0] / 24;

    (void)hipMemsetAsync(out,  0, 67108864, stream);    // sums accumulate here
    (void)hipMemsetAsync(cntb, 0, 1048576, stream);

    transform_w_fp16<<<432, 256, 0, stream>>>(Cw1, wT1);
    transform_w_fp16<<<432, 256, 0, stream>>>(Cw2, wT2);

    const int nblk = 2048;
    point_mlp_scatter<<<nblk, 256, 0, stream>>>(
        pos, pts, W1, b1, W2, b2, Wk1, bk1, Wk2, bk2, out, cntb, np, nblk * 4);

    // conv1: sums (fp32, mean fused) -> c1d (fp16); conv2: c1d -> d_out (fp32)
    conv3d_mfma_p<1><<<512, 256, 64000, stream>>>((const void*)out, cntb, wT1, Cb1, (void*)c1d);
    conv3d_mfma_p<0><<<512, 256, 64000, stream>>>((const void*)c1d, nullptr, wT2, Cb2, (void*)out);
}